// Round 1
// baseline (857.959 us; speedup 1.0000x reference)
//
#include <hip/hip_runtime.h>

// 2-layer GCN: out = relu(gcn2(relu(gcn1(x))))
// gcn(x,W,b)[v] = dinv[v]*( g[v] + sum_{u->v} g[u] ) + b,  g[u]=dinv[u]*(xW)[u]
// dinv[v] = rsqrt(1 + indegree(v))
// Pipeline: degree -> dinv -> CSR(rowptr,col) -> bf16 convert -> GEMM1 -> agg1 -> GEMM2 -> agg2

typedef short          s16x8 __attribute__((ext_vector_type(8)));
typedef float          f32x4 __attribute__((ext_vector_type(4)));
typedef unsigned short u16x4 __attribute__((ext_vector_type(4)));
typedef unsigned short u16x2 __attribute__((ext_vector_type(2)));

__device__ __forceinline__ float bf2f(unsigned short u) {
  union { unsigned int i; float f; } x; x.i = ((unsigned int)u) << 16; return x.f;
}
__device__ __forceinline__ unsigned short f2bf(float f) {
  union { float f; unsigned int i; } x; x.f = f;
  unsigned int r = x.i + 0x7FFFu + ((x.i >> 16) & 1u);
  return (unsigned short)(r >> 16);
}

// ---------------- CSR build ----------------

__global__ void k_zero(int* __restrict__ p, int n) {
  int i = blockIdx.x * 256 + threadIdx.x;
  if (i < n) p[i] = 0;
}

__global__ void k_count(const int* __restrict__ dst, int* __restrict__ deg, int E) {
  int i = blockIdx.x * 256 + threadIdx.x;
  if (i < E) atomicAdd(deg + dst[i], 1);
}

__global__ void k_dinv(const int* __restrict__ deg, float* __restrict__ dinv, int n) {
  int i = blockIdx.x * 256 + threadIdx.x;
  if (i < n) dinv[i] = rsqrtf((float)(deg[i] + 1));   // +1 self loop; always > 0
}

// per-block (256) exclusive scan of deg into rowptr, block totals into sums
__global__ void k_scan1(const int* __restrict__ deg, int* __restrict__ rowptr,
                        int* __restrict__ sums, int n) {
  __shared__ int sh[256];
  int t = threadIdx.x, b = blockIdx.x;
  int i = b * 256 + t;
  int v = (i < n) ? deg[i] : 0;
  sh[t] = v; __syncthreads();
  int x = v;
  for (int off = 1; off < 256; off <<= 1) {
    int y = (t >= off) ? sh[t - off] : 0;
    __syncthreads();
    x += y; sh[t] = x;
    __syncthreads();
  }
  if (i < n) rowptr[i] = x - v;       // exclusive within block
  if (t == 255) sums[b] = x;          // block total
}

// single block: exclusive scan of up to 512 block sums
__global__ void k_scan2(const int* __restrict__ sums, int* __restrict__ offs, int nb) {
  __shared__ int sh[512];
  int t = threadIdx.x;
  int v = (t < nb) ? sums[t] : 0;
  sh[t] = v; __syncthreads();
  int x = v;
  for (int off = 1; off < 512; off <<= 1) {
    int y = (t >= off) ? sh[t - off] : 0;
    __syncthreads();
    x += y; sh[t] = x;
    __syncthreads();
  }
  offs[t] = x - v;
}

__global__ void k_finish(int* __restrict__ rowptr, int* __restrict__ cursor,
                         const int* __restrict__ offs, int n, int E) {
  int i = blockIdx.x * 256 + threadIdx.x;
  if (i < n) {
    int r = rowptr[i] + offs[i >> 8];
    rowptr[i] = r;
    cursor[i] = r;
  }
  if (i == 0) rowptr[n] = E;
}

__global__ void k_fill(const int* __restrict__ src, const int* __restrict__ dst,
                       int* __restrict__ cursor, int* __restrict__ col, int E) {
  int i = blockIdx.x * 256 + threadIdx.x;
  if (i < E) {
    int p = atomicAdd(cursor + dst[i], 1);
    col[p] = src[i];
  }
}

// ---------------- conversions ----------------

__global__ void k_cvt(const float* __restrict__ x, unsigned short* __restrict__ xb, int n4) {
  int i = blockIdx.x * 256 + threadIdx.x;
  if (i < n4) {
    float4 v = ((const float4*)x)[i];
    u16x4 o; o[0] = f2bf(v.x); o[1] = f2bf(v.y); o[2] = f2bf(v.z); o[3] = f2bf(v.w);
    ((u16x4*)xb)[i] = o;
  }
}

// Wt[n*K + k] = bf16(W[k*N + n])
__global__ void k_cvt_wt(const float* __restrict__ W, unsigned short* __restrict__ Wt,
                         int K, int N) {
  int i = blockIdx.x * 256 + threadIdx.x;
  if (i < K * N) {
    int k = i / N, n = i % N;
    Wt[n * K + k] = f2bf(W[i]);
  }
}

// ---------------- GEMM: G = dinv .* (A @ Bt^T), bf16 out ----------------
// A: [M,256] bf16 row-major; Bt: [N,256] bf16 row-major (pre-transposed W).
// Block tile 128x64, 4 waves, each wave 32x64 (2 m-frags x 4 n-frags of 16x16x32).

__device__ __forceinline__ int swz(int row, int kc) { return kc ^ ((row & 3) << 3); }

__global__ __launch_bounds__(256) void k_gemm(
    const unsigned short* __restrict__ A, const unsigned short* __restrict__ Bt,
    const float* __restrict__ dinv, unsigned short* __restrict__ G, int M, int N) {
  const int K = 256;
  __shared__ short lA[128 * 32];
  __shared__ short lB[64 * 32];
  int tid = threadIdx.x;
  int wid = tid >> 6, lane = tid & 63;
  int l15 = lane & 15;
  int lkg = (lane >> 4) * 8;
  int bm = blockIdx.x * 128;
  int bn = blockIdx.y * 64;

  f32x4 acc[2][4] = {};

  for (int kt = 0; kt < 8; ++kt) {
    int k0 = kt * 32;
    __syncthreads();
    // stage A: 512 chunks of 8 bf16
#pragma unroll
    for (int h = 0; h < 2; ++h) {
      int cid = tid + h * 256;
      int r = cid >> 2, kc = (cid & 3) * 8;
      int gr = bm + r;
      s16x8 v = {0, 0, 0, 0, 0, 0, 0, 0};
      if (gr < M) v = *(const s16x8*)(A + (size_t)gr * K + k0 + kc);
      *(s16x8*)(&lA[r * 32 + swz(r, kc)]) = v;
    }
    // stage B: 256 chunks
    {
      int c = tid >> 2, kc = (tid & 3) * 8;
      s16x8 v = *(const s16x8*)(Bt + (size_t)(bn + c) * K + k0 + kc);
      *(s16x8*)(&lB[c * 32 + swz(c, kc)]) = v;
    }
    __syncthreads();

    s16x8 af[2], bfr[4];
#pragma unroll
    for (int mi = 0; mi < 2; ++mi) {
      int r = wid * 32 + mi * 16 + l15;
      af[mi] = *(const s16x8*)(&lA[r * 32 + swz(r, lkg)]);
    }
#pragma unroll
    for (int ni = 0; ni < 4; ++ni) {
      int c = ni * 16 + l15;
      bfr[ni] = *(const s16x8*)(&lB[c * 32 + swz(c, lkg)]);
    }
#pragma unroll
    for (int mi = 0; mi < 2; ++mi)
#pragma unroll
      for (int ni = 0; ni < 4; ++ni)
        acc[mi][ni] = __builtin_amdgcn_mfma_f32_16x16x32_bf16(af[mi], bfr[ni], acc[mi][ni], 0, 0, 0);
  }

  // epilogue: C/D layout col=lane&15, row=(lane>>4)*4+reg
#pragma unroll
  for (int mi = 0; mi < 2; ++mi) {
    int mrow0 = bm + wid * 32 + mi * 16 + (lane >> 4) * 4;
#pragma unroll
    for (int j = 0; j < 4; ++j) {
      int m = mrow0 + j;
      if (m < M) {
        float dv = dinv[m];
#pragma unroll
        for (int ni = 0; ni < 4; ++ni) {
          float val = acc[mi][ni][j] * dv;
          G[(size_t)m * N + bn + ni * 16 + l15] = f2bf(val);
        }
      }
    }
  }
}

// ---------------- aggregation: one wave per node ----------------

// 256-dim: H[v] = bf16(relu(dinv[v]*(G[v] + sum G[col[j]]) + bias))
__global__ __launch_bounds__(256) void k_agg256(
    const unsigned short* __restrict__ G, const int* __restrict__ rowptr,
    const int* __restrict__ col, const float* __restrict__ dinv,
    const float* __restrict__ bias, unsigned short* __restrict__ H, int M) {
  int lane = threadIdx.x & 63;
  int v = (blockIdx.x << 2) + (threadIdx.x >> 6);
  if (v >= M) return;
  int c4 = lane * 4;
  size_t base = (size_t)v * 256 + c4;
  float a0, a1, a2, a3;
  {
    u16x4 s = *(const u16x4*)(G + base);
    a0 = bf2f(s[0]); a1 = bf2f(s[1]); a2 = bf2f(s[2]); a3 = bf2f(s[3]);
  }
  int jb = rowptr[v], je = rowptr[v + 1];
  int j = jb;
  for (; j + 3 < je; j += 4) {
    int u0 = col[j], u1 = col[j + 1], u2 = col[j + 2], u3 = col[j + 3];
    u16x4 p0 = *(const u16x4*)(G + (size_t)u0 * 256 + c4);
    u16x4 p1 = *(const u16x4*)(G + (size_t)u1 * 256 + c4);
    u16x4 p2 = *(const u16x4*)(G + (size_t)u2 * 256 + c4);
    u16x4 p3 = *(const u16x4*)(G + (size_t)u3 * 256 + c4);
    a0 += bf2f(p0[0]) + bf2f(p1[0]) + bf2f(p2[0]) + bf2f(p3[0]);
    a1 += bf2f(p0[1]) + bf2f(p1[1]) + bf2f(p2[1]) + bf2f(p3[1]);
    a2 += bf2f(p0[2]) + bf2f(p1[2]) + bf2f(p2[2]) + bf2f(p3[2]);
    a3 += bf2f(p0[3]) + bf2f(p1[3]) + bf2f(p2[3]) + bf2f(p3[3]);
  }
  for (; j < je; ++j) {
    int u = col[j];
    u16x4 p = *(const u16x4*)(G + (size_t)u * 256 + c4);
    a0 += bf2f(p[0]); a1 += bf2f(p[1]); a2 += bf2f(p[2]); a3 += bf2f(p[3]);
  }
  float dv = dinv[v];
  float4 bb = *(const float4*)(bias + c4);
  u16x4 o;
  o[0] = f2bf(fmaxf(fmaf(dv, a0, bb.x), 0.f));
  o[1] = f2bf(fmaxf(fmaf(dv, a1, bb.y), 0.f));
  o[2] = f2bf(fmaxf(fmaf(dv, a2, bb.z), 0.f));
  o[3] = f2bf(fmaxf(fmaf(dv, a3, bb.w), 0.f));
  *(u16x4*)(H + base) = o;
}

// 128-dim, fp32 output
__global__ __launch_bounds__(256) void k_agg128(
    const unsigned short* __restrict__ G, const int* __restrict__ rowptr,
    const int* __restrict__ col, const float* __restrict__ dinv,
    const float* __restrict__ bias, float* __restrict__ Out, int M) {
  int lane = threadIdx.x & 63;
  int v = (blockIdx.x << 2) + (threadIdx.x >> 6);
  if (v >= M) return;
  int c2 = lane * 2;
  size_t base = (size_t)v * 128 + c2;
  float a0, a1;
  {
    u16x2 s = *(const u16x2*)(G + base);
    a0 = bf2f(s[0]); a1 = bf2f(s[1]);
  }
  int jb = rowptr[v], je = rowptr[v + 1];
  int j = jb;
  for (; j + 3 < je; j += 4) {
    int u0 = col[j], u1 = col[j + 1], u2 = col[j + 2], u3 = col[j + 3];
    u16x2 p0 = *(const u16x2*)(G + (size_t)u0 * 128 + c2);
    u16x2 p1 = *(const u16x2*)(G + (size_t)u1 * 128 + c2);
    u16x2 p2 = *(const u16x2*)(G + (size_t)u2 * 128 + c2);
    u16x2 p3 = *(const u16x2*)(G + (size_t)u3 * 128 + c2);
    a0 += bf2f(p0[0]) + bf2f(p1[0]) + bf2f(p2[0]) + bf2f(p3[0]);
    a1 += bf2f(p0[1]) + bf2f(p1[1]) + bf2f(p2[1]) + bf2f(p3[1]);
  }
  for (; j < je; ++j) {
    int u = col[j];
    u16x2 p = *(const u16x2*)(G + (size_t)u * 128 + c2);
    a0 += bf2f(p[0]); a1 += bf2f(p[1]);
  }
  float dv = dinv[v];
  float2 r;
  r.x = fmaxf(fmaf(dv, a0, bias[c2 + 0]), 0.f);
  r.y = fmaxf(fmaf(dv, a1, bias[c2 + 1]), 0.f);
  *(float2*)(Out + base) = r;
}

// ---------------- launch ----------------

extern "C" void kernel_launch(void* const* d_in, const int* in_sizes, int n_in,
                              void* d_out, int out_size, void* d_ws, size_t ws_size,
                              hipStream_t stream) {
  const float* x  = (const float*)d_in[0];
  const float* W1 = (const float*)d_in[1];
  const float* b1 = (const float*)d_in[2];
  const float* W2 = (const float*)d_in[3];
  const float* b2 = (const float*)d_in[4];
  const int*   ei = (const int*)d_in[5];

  const int D_IN = 256, D_HID = 256, D_OUT = 128;
  const int M = in_sizes[0] / D_IN;    // 100000
  const int E = in_sizes[5] / 2;       // 3200000
  const int* src = ei;
  const int* dst = ei + E;

  char* p = (char*)d_ws;
  auto alloc = [&](size_t bytes) { void* r = (void*)p; p += (bytes + 255) & ~(size_t)255; return r; };
  int*   deg    = (int*)alloc((size_t)M * 4);
  float* dinv   = (float*)alloc((size_t)M * 4);
  int*   rowptr = (int*)alloc((size_t)(M + 1) * 4);
  int*   cursor = (int*)alloc((size_t)M * 4);
  int*   sums   = (int*)alloc(512 * 4);
  int*   offs   = (int*)alloc(512 * 4);
  int*   colx   = (int*)alloc((size_t)E * 4);
  unsigned short* xb  = (unsigned short*)alloc((size_t)M * D_IN * 2);   // reused as g2
  unsigned short* w1t = (unsigned short*)alloc((size_t)D_HID * D_IN * 2);
  unsigned short* w2t = (unsigned short*)alloc((size_t)D_OUT * D_HID * 2);
  unsigned short* g1  = (unsigned short*)alloc((size_t)M * D_HID * 2);
  unsigned short* hid = (unsigned short*)alloc((size_t)M * D_HID * 2);
  unsigned short* g2  = xb;  // xb dead after GEMM1

  int nb  = (M + 255) / 256;           // 391 (<=512 for scan2)
  int ebl = (E + 255) / 256;

  k_zero  <<<nb, 256, 0, stream>>>(deg, M);
  k_count <<<ebl, 256, 0, stream>>>(dst, deg, E);
  k_dinv  <<<nb, 256, 0, stream>>>(deg, dinv, M);
  k_scan1 <<<nb, 256, 0, stream>>>(deg, rowptr, sums, M);
  k_scan2 <<<1, 512, 0, stream>>>(sums, offs, nb);
  k_finish<<<nb, 256, 0, stream>>>(rowptr, cursor, offs, M, E);
  k_fill  <<<ebl, 256, 0, stream>>>(src, dst, cursor, colx, E);

  k_cvt   <<<(M * D_IN / 4 + 255) / 256, 256, 0, stream>>>(x, xb, M * D_IN / 4);
  k_cvt_wt<<<(D_IN * D_HID + 255) / 256, 256, 0, stream>>>(W1, w1t, D_IN, D_HID);
  k_cvt_wt<<<(D_HID * D_OUT + 255) / 256, 256, 0, stream>>>(W2, w2t, D_HID, D_OUT);

  dim3 gg1((M + 127) / 128, D_HID / 64);
  k_gemm  <<<gg1, 256, 0, stream>>>(xb, w1t, dinv, g1, M, D_HID);
  k_agg256<<<(M + 3) / 4, 256, 0, stream>>>(g1, rowptr, colx, dinv, b1, hid, M);

  dim3 gg2((M + 127) / 128, D_OUT / 64);
  k_gemm  <<<gg2, 256, 0, stream>>>(hid, w2t, dinv, g2, M, D_OUT);
  k_agg128<<<(M + 3) / 4, 256, 0, stream>>>(g2, rowptr, colx, dinv, b2, (float*)d_out, M);
}

// Round 2
// 577.269 us; speedup vs baseline: 1.4862x; 1.4862x over previous
//
#include <hip/hip_runtime.h>

// 2-layer GCN: out = relu(gcn2(relu(gcn1(x))))
// gcn(x,W,b)[v] = dinv[v]*( g[v] + sum_{u->v} g[u] ) + b,  g[u]=dinv[u]*(xW)[u]
// dinv[v] = rsqrt(1 + indegree(v))
// CSR build via 782-bucket counting sort (bucket = dst>>7, contiguous node ranges
// so bucket regions ARE the final CSR col regions).

typedef short          s16x8 __attribute__((ext_vector_type(8)));
typedef float          f32x4 __attribute__((ext_vector_type(4)));
typedef unsigned short u16x4 __attribute__((ext_vector_type(4)));
typedef unsigned short u16x2 __attribute__((ext_vector_type(2)));

__device__ __forceinline__ float bf2f(unsigned short u) {
  union { unsigned int i; float f; } x; x.i = ((unsigned int)u) << 16; return x.f;
}
__device__ __forceinline__ unsigned short f2bf(float f) {
  union { float f; unsigned int i; } x; x.f = f;
  unsigned int r = x.i + 0x7FFFu + ((x.i >> 16) & 1u);
  return (unsigned short)(r >> 16);
}

// ---------------- CSR build (bucketed counting sort) ----------------

#define NBUCK_PAD 1024   // buckets used: ceil(M/128) = 782
#define BIN_CHUNK 8192

__global__ void k_zero1024(int* __restrict__ p) { p[threadIdx.x + blockIdx.x * 256] = 0; }

__global__ __launch_bounds__(256) void k_hist(const int* __restrict__ dst,
                                              int* __restrict__ bcnt, int E) {
  __shared__ int h[NBUCK_PAD];
  int t = threadIdx.x;
  for (int i = t; i < NBUCK_PAD; i += 256) h[i] = 0;
  __syncthreads();
  int stride = gridDim.x * 256;
  for (int e = blockIdx.x * 256 + t; e < E; e += stride) atomicAdd(&h[dst[e] >> 7], 1);
  __syncthreads();
  for (int i = t; i < NBUCK_PAD; i += 256) {
    int v = h[i];
    if (v) atomicAdd(bcnt + i, v);
  }
}

// single block, 1024 threads: exclusive scan of bucket counts; also rowptr[M]=E
__global__ void k_bscan(const int* __restrict__ bcnt, int* __restrict__ bptr,
                        int* __restrict__ bcur, int* __restrict__ rowptr, int M, int E) {
  __shared__ int sh[NBUCK_PAD];
  int t = threadIdx.x;
  int v = bcnt[t];
  sh[t] = v; __syncthreads();
  int x = v;
  for (int off = 1; off < NBUCK_PAD; off <<= 1) {
    int y = (t >= off) ? sh[t - off] : 0;
    __syncthreads();
    x += y; sh[t] = x;
    __syncthreads();
  }
  bptr[t] = x - v;
  bcur[t] = x - v;
  if (t == NBUCK_PAD - 1) bptr[NBUCK_PAD] = x;
  if (t == 0) rowptr[M] = E;
}

// bin edges: packed val = (dst&127)<<17 | src  (src < 2^17)
__global__ __launch_bounds__(256) void k_bin(const int* __restrict__ src,
                                             const int* __restrict__ dst,
                                             int* __restrict__ bcur,
                                             unsigned int* __restrict__ binned, int E) {
  __shared__ int hist[NBUCK_PAD];
  __shared__ int base[NBUCK_PAD];
  int t = threadIdx.x;
  int e0 = blockIdx.x * BIN_CHUNK;
  int e1 = min(e0 + BIN_CHUNK, E);
  for (int i = t; i < NBUCK_PAD; i += 256) hist[i] = 0;
  __syncthreads();
  for (int e = e0 + t; e < e1; e += 256) atomicAdd(&hist[dst[e] >> 7], 1);
  __syncthreads();
  for (int i = t; i < NBUCK_PAD; i += 256) {
    int h = hist[i];
    base[i] = h ? atomicAdd(bcur + i, h) : 0;
    hist[i] = 0;  // reuse as local cursor
  }
  __syncthreads();
  for (int e = e0 + t; e < e1; e += 256) {
    int d = dst[e], s = src[e];
    int b = d >> 7;
    int p = base[b] + atomicAdd(&hist[b], 1);
    binned[p] = ((unsigned)(d & 127) << 17) | (unsigned)s;
  }
}

// one block per bucket: per-node degree, rowptr, dinv, and col scatter (LDS cursors)
__global__ __launch_bounds__(256) void k_csr(const unsigned int* __restrict__ binned,
                                             const int* __restrict__ bptr,
                                             int* __restrict__ rowptr,
                                             float* __restrict__ dinv,
                                             int* __restrict__ col, int M) {
  __shared__ int deg[128];
  __shared__ int sc[128];
  __shared__ int cur[128];
  int b = blockIdx.x, t = threadIdx.x;
  int n0 = b << 7;
  int nn = min(128, M - n0);
  int e0 = bptr[b], e1 = bptr[b + 1];
  if (t < 128) deg[t] = 0;
  __syncthreads();
  for (int e = e0 + t; e < e1; e += 256) atomicAdd(&deg[(binned[e] >> 17) & 127], 1);
  __syncthreads();
  if (t < 128) sc[t] = deg[t];
  __syncthreads();
  for (int off = 1; off < 128; off <<= 1) {
    int y = 0;
    if (t < 128 && t >= off) y = sc[t - off];
    __syncthreads();
    if (t < 128) sc[t] += y;
    __syncthreads();
  }
  if (t < nn) {
    int excl = sc[t] - deg[t];
    rowptr[n0 + t] = e0 + excl;
    dinv[n0 + t] = rsqrtf((float)(deg[t] + 1));
    cur[t] = excl;
  }
  __syncthreads();
  for (int e = e0 + t; e < e1; e += 256) {
    unsigned v = binned[e];
    int dl = (v >> 17) & 127;
    int p = e0 + atomicAdd(&cur[dl], 1);
    col[p] = (int)(v & 0x1FFFFu);
  }
}

// ---------------- conversions ----------------

__global__ void k_cvt(const float* __restrict__ x, unsigned short* __restrict__ xb, int n4) {
  int i = blockIdx.x * 256 + threadIdx.x;
  if (i < n4) {
    float4 v = ((const float4*)x)[i];
    u16x4 o; o[0] = f2bf(v.x); o[1] = f2bf(v.y); o[2] = f2bf(v.z); o[3] = f2bf(v.w);
    ((u16x4*)xb)[i] = o;
  }
}

__global__ void k_cvt_wt(const float* __restrict__ W, unsigned short* __restrict__ Wt,
                         int K, int N) {
  int i = blockIdx.x * 256 + threadIdx.x;
  if (i < K * N) {
    int k = i / N, n = i % N;
    Wt[n * K + k] = f2bf(W[i]);
  }
}

// ---------------- GEMM: G = dinv .* (A @ Bt^T), bf16 out ----------------

__device__ __forceinline__ int swz(int row, int kc) { return kc ^ ((row & 3) << 3); }

__global__ __launch_bounds__(256) void k_gemm(
    const unsigned short* __restrict__ A, const unsigned short* __restrict__ Bt,
    const float* __restrict__ dinv, unsigned short* __restrict__ G, int M, int N) {
  const int K = 256;
  __shared__ short lA[128 * 32];
  __shared__ short lB[64 * 32];
  int tid = threadIdx.x;
  int wid = tid >> 6, lane = tid & 63;
  int l15 = lane & 15;
  int lkg = (lane >> 4) * 8;
  int bm = blockIdx.x * 128;
  int bn = blockIdx.y * 64;

  f32x4 acc[2][4] = {};

  for (int kt = 0; kt < 8; ++kt) {
    int k0 = kt * 32;
    __syncthreads();
#pragma unroll
    for (int h = 0; h < 2; ++h) {
      int cid = tid + h * 256;
      int r = cid >> 2, kc = (cid & 3) * 8;
      int gr = bm + r;
      s16x8 v = {0, 0, 0, 0, 0, 0, 0, 0};
      if (gr < M) v = *(const s16x8*)(A + (size_t)gr * K + k0 + kc);
      *(s16x8*)(&lA[r * 32 + swz(r, kc)]) = v;
    }
    {
      int c = tid >> 2, kc = (tid & 3) * 8;
      s16x8 v = *(const s16x8*)(Bt + (size_t)(bn + c) * K + k0 + kc);
      *(s16x8*)(&lB[c * 32 + swz(c, kc)]) = v;
    }
    __syncthreads();

    s16x8 af[2], bfr[4];
#pragma unroll
    for (int mi = 0; mi < 2; ++mi) {
      int r = wid * 32 + mi * 16 + l15;
      af[mi] = *(const s16x8*)(&lA[r * 32 + swz(r, lkg)]);
    }
#pragma unroll
    for (int ni = 0; ni < 4; ++ni) {
      int c = ni * 16 + l15;
      bfr[ni] = *(const s16x8*)(&lB[c * 32 + swz(c, lkg)]);
    }
#pragma unroll
    for (int mi = 0; mi < 2; ++mi)
#pragma unroll
      for (int ni = 0; ni < 4; ++ni)
        acc[mi][ni] = __builtin_amdgcn_mfma_f32_16x16x32_bf16(af[mi], bfr[ni], acc[mi][ni], 0, 0, 0);
  }

#pragma unroll
  for (int mi = 0; mi < 2; ++mi) {
    int mrow0 = bm + wid * 32 + mi * 16 + (lane >> 4) * 4;
#pragma unroll
    for (int j = 0; j < 4; ++j) {
      int m = mrow0 + j;
      if (m < M) {
        float dv = dinv[m];
#pragma unroll
        for (int ni = 0; ni < 4; ++ni) {
          float val = acc[mi][ni][j] * dv;
          G[(size_t)m * N + bn + ni * 16 + l15] = f2bf(val);
        }
      }
    }
  }
}

// ---------------- aggregation: one wave per node ----------------

__global__ __launch_bounds__(256) void k_agg256(
    const unsigned short* __restrict__ G, const int* __restrict__ rowptr,
    const int* __restrict__ col, const float* __restrict__ dinv,
    const float* __restrict__ bias, unsigned short* __restrict__ H, int M) {
  int lane = threadIdx.x & 63;
  int v = (blockIdx.x << 2) + (threadIdx.x >> 6);
  if (v >= M) return;
  int c4 = lane * 4;
  size_t base = (size_t)v * 256 + c4;
  float a0, a1, a2, a3;
  {
    u16x4 s = *(const u16x4*)(G + base);
    a0 = bf2f(s[0]); a1 = bf2f(s[1]); a2 = bf2f(s[2]); a3 = bf2f(s[3]);
  }
  int jb = rowptr[v], je = rowptr[v + 1];
  int j = jb;
  for (; j + 3 < je; j += 4) {
    int u0 = col[j], u1 = col[j + 1], u2 = col[j + 2], u3 = col[j + 3];
    u16x4 p0 = *(const u16x4*)(G + (size_t)u0 * 256 + c4);
    u16x4 p1 = *(const u16x4*)(G + (size_t)u1 * 256 + c4);
    u16x4 p2 = *(const u16x4*)(G + (size_t)u2 * 256 + c4);
    u16x4 p3 = *(const u16x4*)(G + (size_t)u3 * 256 + c4);
    a0 += bf2f(p0[0]) + bf2f(p1[0]) + bf2f(p2[0]) + bf2f(p3[0]);
    a1 += bf2f(p0[1]) + bf2f(p1[1]) + bf2f(p2[1]) + bf2f(p3[1]);
    a2 += bf2f(p0[2]) + bf2f(p1[2]) + bf2f(p2[2]) + bf2f(p3[2]);
    a3 += bf2f(p0[3]) + bf2f(p1[3]) + bf2f(p2[3]) + bf2f(p3[3]);
  }
  for (; j < je; ++j) {
    int u = col[j];
    u16x4 p = *(const u16x4*)(G + (size_t)u * 256 + c4);
    a0 += bf2f(p[0]); a1 += bf2f(p[1]); a2 += bf2f(p[2]); a3 += bf2f(p[3]);
  }
  float dv = dinv[v];
  float4 bb = *(const float4*)(bias + c4);
  u16x4 o;
  o[0] = f2bf(fmaxf(fmaf(dv, a0, bb.x), 0.f));
  o[1] = f2bf(fmaxf(fmaf(dv, a1, bb.y), 0.f));
  o[2] = f2bf(fmaxf(fmaf(dv, a2, bb.z), 0.f));
  o[3] = f2bf(fmaxf(fmaf(dv, a3, bb.w), 0.f));
  *(u16x4*)(H + base) = o;
}

__global__ __launch_bounds__(256) void k_agg128(
    const unsigned short* __restrict__ G, const int* __restrict__ rowptr,
    const int* __restrict__ col, const float* __restrict__ dinv,
    const float* __restrict__ bias, float* __restrict__ Out, int M) {
  int lane = threadIdx.x & 63;
  int v = (blockIdx.x << 2) + (threadIdx.x >> 6);
  if (v >= M) return;
  int c2 = lane * 2;
  size_t base = (size_t)v * 128 + c2;
  float a0, a1;
  {
    u16x2 s = *(const u16x2*)(G + base);
    a0 = bf2f(s[0]); a1 = bf2f(s[1]);
  }
  int jb = rowptr[v], je = rowptr[v + 1];
  int j = jb;
  for (; j + 3 < je; j += 4) {
    int u0 = col[j], u1 = col[j + 1], u2 = col[j + 2], u3 = col[j + 3];
    u16x2 p0 = *(const u16x2*)(G + (size_t)u0 * 128 + c2);
    u16x2 p1 = *(const u16x2*)(G + (size_t)u1 * 128 + c2);
    u16x2 p2 = *(const u16x2*)(G + (size_t)u2 * 128 + c2);
    u16x2 p3 = *(const u16x2*)(G + (size_t)u3 * 128 + c2);
    a0 += bf2f(p0[0]) + bf2f(p1[0]) + bf2f(p2[0]) + bf2f(p3[0]);
    a1 += bf2f(p0[1]) + bf2f(p1[1]) + bf2f(p2[1]) + bf2f(p3[1]);
  }
  for (; j < je; ++j) {
    int u = col[j];
    u16x2 p = *(const u16x2*)(G + (size_t)u * 128 + c2);
    a0 += bf2f(p[0]); a1 += bf2f(p[1]);
  }
  float dv = dinv[v];
  float2 r;
  r.x = fmaxf(fmaf(dv, a0, bias[c2 + 0]), 0.f);
  r.y = fmaxf(fmaf(dv, a1, bias[c2 + 1]), 0.f);
  *(float2*)(Out + base) = r;
}

// ---------------- launch ----------------

extern "C" void kernel_launch(void* const* d_in, const int* in_sizes, int n_in,
                              void* d_out, int out_size, void* d_ws, size_t ws_size,
                              hipStream_t stream) {
  const float* x  = (const float*)d_in[0];
  const float* W1 = (const float*)d_in[1];
  const float* b1 = (const float*)d_in[2];
  const float* W2 = (const float*)d_in[3];
  const float* b2 = (const float*)d_in[4];
  const int*   ei = (const int*)d_in[5];

  const int D_IN = 256, D_HID = 256, D_OUT = 128;
  const int M = in_sizes[0] / D_IN;    // 100000
  const int E = in_sizes[5] / 2;       // 3200000
  const int* src = ei;
  const int* dst = ei + E;

  char* p = (char*)d_ws;
  auto alloc = [&](size_t bytes) { void* r = (void*)p; p += (bytes + 255) & ~(size_t)255; return r; };
  float* dinv = (float*)alloc((size_t)M * 4);
  int* rowptr = (int*)alloc((size_t)(M + 1) * 4);
  int* bcnt   = (int*)alloc(NBUCK_PAD * 4);
  int* bptr   = (int*)alloc((NBUCK_PAD + 1) * 4);
  int* bcur   = (int*)alloc(NBUCK_PAD * 4);
  int* colx   = (int*)alloc((size_t)E * 4);
  unsigned short* xb  = (unsigned short*)alloc((size_t)M * D_IN * 2);   // reused as g2
  unsigned short* w1t = (unsigned short*)alloc((size_t)D_HID * D_IN * 2);
  unsigned short* w2t = (unsigned short*)alloc((size_t)D_OUT * D_HID * 2);
  unsigned short* g1  = (unsigned short*)alloc((size_t)M * D_HID * 2);
  unsigned short* hid = (unsigned short*)alloc((size_t)M * D_HID * 2);
  unsigned short* g2  = xb;                       // xb dead after GEMM1
  unsigned int* binned = (unsigned int*)hid;      // hid dead until agg1; binned dead after k_csr

  int nbuck = (M + 127) >> 7;                     // 782
  int nbin  = (E + BIN_CHUNK - 1) / BIN_CHUNK;    // 391

  k_zero1024<<<4, 256, 0, stream>>>(bcnt);
  k_hist <<<256, 256, 0, stream>>>(dst, bcnt, E);
  k_bscan<<<1, NBUCK_PAD, 0, stream>>>(bcnt, bptr, bcur, rowptr, M, E);
  k_bin  <<<nbin, 256, 0, stream>>>(src, dst, bcur, binned, E);
  k_csr  <<<nbuck, 256, 0, stream>>>(binned, bptr, rowptr, dinv, colx, M);

  k_cvt   <<<(M * D_IN / 4 + 255) / 256, 256, 0, stream>>>(x, xb, M * D_IN / 4);
  k_cvt_wt<<<(D_IN * D_HID + 255) / 256, 256, 0, stream>>>(W1, w1t, D_IN, D_HID);
  k_cvt_wt<<<(D_HID * D_OUT + 255) / 256, 256, 0, stream>>>(W2, w2t, D_HID, D_OUT);

  dim3 gg1((M + 127) / 128, D_HID / 64);
  k_gemm  <<<gg1, 256, 0, stream>>>(xb, w1t, dinv, g1, M, D_HID);
  k_agg256<<<(M + 3) / 4, 256, 0, stream>>>(g1, rowptr, colx, dinv, b1, hid, M);

  dim3 gg2((M + 127) / 128, D_OUT / 64);
  k_gemm  <<<gg2, 256, 0, stream>>>(hid, w2t, dinv, g2, M, D_OUT);
  k_agg128<<<(M + 3) / 4, 256, 0, stream>>>(g2, rowptr, colx, dinv, b2, (float*)d_out, M);
}